// Round 2
// 1318.063 us; speedup vs baseline: 1.0367x; 1.0367x over previous
//
#include <hip/hip_runtime.h>

#define B_ 2
#define S_ 2048
#define HID_ 4096
#define NH_ 32
#define NKV_ 8
#define D_ 128
#define M_ (B_*S_)                  // 4096 rows of hidden
#define NQKV_ (HID_ + 2*NKV_*D_)    // 6144

typedef __bf16 v8bf __attribute__((ext_vector_type(8)));
typedef float  v4f  __attribute__((ext_vector_type(4)));

__device__ __forceinline__ unsigned short f2bf(float x) {
    unsigned u = __float_as_uint(x);
    u += 0x7FFFu + ((u >> 16) & 1u);   // RNE
    return (unsigned short)(u >> 16);
}
__device__ __forceinline__ float bf2f(unsigned short h) {
    return __uint_as_float(((unsigned)h) << 16);
}

// async global->LDS, 16B per lane. LDS dest must be WAVE-UNIFORM base;
// HW writes base + lane*16. Global address is per-lane.
__device__ __forceinline__ void gl_lds16(const unsigned short* g, unsigned short* l) {
    __builtin_amdgcn_global_load_lds(
        (const __attribute__((address_space(1))) void*)g,
        (__attribute__((address_space(3))) void*)l, 16, 0, 0);
}

// ---------------- fp32 -> bf16 elementwise convert (x4 vectorized) ---------
__global__ __launch_bounds__(256)
void cvt_f32_bf16(const float* __restrict__ src, unsigned short* __restrict__ dst, int n4) {
    int i = blockIdx.x * 256 + threadIdx.x;
    if (i >= n4) return;
    float4 v = ((const float4*)src)[i];
    ushort4 o;
    o.x = f2bf(v.x); o.y = f2bf(v.y); o.z = f2bf(v.z); o.w = f2bf(v.w);
    ((ushort4*)dst)[i] = o;
}

// ------------- transpose+convert: dst[n][k] = bf16(src[k][n]), fp32 src ----
__global__ __launch_bounds__(256)
void transpose_f32_bf16(const float* __restrict__ src,
                        unsigned short* __restrict__ dst, int K, int N) {
    __shared__ unsigned short tile[64][65];
    int n0 = blockIdx.x * 64, k0 = blockIdx.y * 64;
    int tid = threadIdx.x;
    for (int i = 0; i < 16; ++i) {
        int fi = tid + i * 256;
        int r = fi >> 6, c = fi & 63;
        tile[r][c] = f2bf(src[(size_t)(k0 + r) * N + n0 + c]);
    }
    __syncthreads();
    for (int i = 0; i < 16; ++i) {
        int fi = tid + i * 256;
        int r = fi >> 6, c = fi & 63;
        dst[(size_t)(n0 + r) * K + k0 + c] = tile[c][r];
    }
}

// ------------- per-head V transpose: [BHkv][S][D] -> [BHkv][D][S] bf16 -----
__global__ __launch_bounds__(256)
void transpose_v(const unsigned short* __restrict__ src,
                 unsigned short* __restrict__ dst) {
    __shared__ unsigned short tile[64][65];
    int s0 = blockIdx.x * 64, d0 = blockIdx.y * 64;
    size_t base = (size_t)blockIdx.z * S_ * D_;
    int tid = threadIdx.x;
    for (int i = 0; i < 16; ++i) {
        int fi = tid + i * 256;
        int r = fi >> 6, c = fi & 63;            // r: s-offset, c: d-offset
        tile[r][c] = src[base + (size_t)(s0 + r) * D_ + d0 + c];
    }
    __syncthreads();
    for (int i = 0; i < 16; ++i) {
        int fi = tid + i * 256;
        int r = fi >> 6, c = fi & 63;            // r: d-offset, c: s-offset
        dst[base + (size_t)(d0 + r) * S_ + s0 + c] = tile[c][r];
    }
}

// ---------------- GEMM: C[M][N] = A[M][K] * BT[N][K]^T  (bf16 in, fp32 acc) -
// m97 structure: global_load_lds width-16 staging into LINEAR (unpadded) LDS,
// 2 barriers per K-step. MODE 0: scatter epilogue into Q/K/V per-head bf16
// buffers (pre-RoPE). MODE 1: fp32 store to outF, row stride HID_.
template <int MODE>
__global__ __launch_bounds__(256)
void gemm_bt(const unsigned short* __restrict__ A,
             const unsigned short* __restrict__ BT,
             int K, int lda, int ldb,
             unsigned short* __restrict__ outQ,
             unsigned short* __restrict__ outK,
             unsigned short* __restrict__ outV,
             float* __restrict__ outF) {
    __shared__ unsigned short As[128][32];   // linear: gl_lds dest is base+lane*16
    __shared__ unsigned short Bs[128][32];
    int tid = threadIdx.x;
    int lane = tid & 63, wid = tid >> 6;
    int quad = lane >> 4, l16 = lane & 15;
    int wr = wid >> 1, wc = wid & 1;
    int r0 = blockIdx.y * 128, n0 = blockIdx.x * 128;

    v4f zero = {0.f, 0.f, 0.f, 0.f};
    v4f acc[4][4];
    for (int i = 0; i < 4; ++i) for (int j = 0; j < 4; ++j) acc[i][j] = zero;

    // staging geometry: wave wid owns tile rows [wid*32, wid*32+32).
    // each gl_lds call covers 16 rows (64 lanes x 16B = 1KB = 16 x 64B rows).
    const int srow = wid * 32 + (lane >> 2);      // per-lane source row within tile
    const int sch  = (lane & 3) * 8;              // 16B chunk (8 shorts)
    const unsigned short* gA = &A [(size_t)(r0 + srow) * lda + sch];
    const unsigned short* gB = &BT[(size_t)(n0 + srow) * ldb + sch];
    unsigned short* lA0 = &As[wid * 32][0];
    unsigned short* lA1 = &As[wid * 32 + 16][0];
    unsigned short* lB0 = &Bs[wid * 32][0];
    unsigned short* lB1 = &Bs[wid * 32 + 16][0];

    for (int kt = 0; kt < K / 32; ++kt) {
        int kk = kt * 32;
        gl_lds16(gA + kk, lA0);
        gl_lds16(gA + (size_t)16 * lda + kk, lA1);
        gl_lds16(gB + kk, lB0);
        gl_lds16(gB + (size_t)16 * ldb + kk, lB1);
        __syncthreads();                          // compiler drains vmcnt before barrier
        v8bf av[4], bv[4];
        for (int ms = 0; ms < 4; ++ms) av[ms] = *(const v8bf*)&As[wr * 64 + ms * 16 + l16][quad * 8];
        for (int ns = 0; ns < 4; ++ns) bv[ns] = *(const v8bf*)&Bs[wc * 64 + ns * 16 + l16][quad * 8];
        for (int ms = 0; ms < 4; ++ms)
            for (int ns = 0; ns < 4; ++ns)
                acc[ms][ns] = __builtin_amdgcn_mfma_f32_16x16x32_bf16(av[ms], bv[ns], acc[ms][ns], 0, 0, 0);
        __syncthreads();                          // readers done before next overwrite
    }

    for (int ms = 0; ms < 4; ++ms)
        for (int ns = 0; ns < 4; ++ns)
            for (int r = 0; r < 4; ++r) {
                int row = r0 + wr * 64 + ms * 16 + quad * 4 + r;   // C row = quad*4+reg (m89)
                int col = n0 + wc * 64 + ns * 16 + l16;            // C col = lane&15
                if (MODE == 1) {
                    outF[(size_t)row * HID_ + col] = acc[ms][ns][r];
                } else {
                    unsigned short hv = f2bf(acc[ms][ns][r]);
                    int b = row >> 11, s = row & (S_ - 1);
                    if (col < HID_) {
                        int h = col >> 7, d = col & 127;
                        outQ[((size_t)((b * NH_ + h) * S_ + s)) * D_ + d] = hv;
                    } else if (col < HID_ + NKV_ * D_) {
                        int j = col - HID_; int h = j >> 7, d = j & 127;
                        outK[((size_t)((b * NKV_ + h) * S_ + s)) * D_ + d] = hv;
                    } else {
                        int j = col - HID_ - NKV_ * D_; int h = j >> 7, d = j & 127;
                        outV[((size_t)((b * NKV_ + h) * S_ + s)) * D_ + d] = hv;
                    }
                }
            }
}

// ---------------- RoPE in-place on [BH][S][D] bf16, fp32 cos/sin ----------
__global__ __launch_bounds__(256)
void rope_kernel(unsigned short* __restrict__ buf,
                 const float* __restrict__ cosc,
                 const float* __restrict__ sinc, int total) {
    int idx = blockIdx.x * 256 + threadIdx.x;
    if (idx >= total) return;
    int d2 = idx & 63;
    int s  = (idx >> 6) & (S_ - 1);
    int bh = idx >> 17;                       // /(64*2048)
    size_t base = ((size_t)bh * S_ + s) * D_;
    float c  = cosc[s * D_ + d2];             // cos[s][d2] == cos[s][d2+64]
    float sn = sinc[s * D_ + d2];
    float x1 = bf2f(buf[base + d2]);
    float x2 = bf2f(buf[base + d2 + 64]);
    buf[base + d2]      = f2bf(x1 * c - x2 * sn);
    buf[base + d2 + 64] = f2bf(x2 * c + x1 * sn);
}

// ---------------- causal flash attention v2 --------------------------------
// grid: (S/64, NH, B). block: 256 (4 waves x 16 q-rows). KV tile = 64 keys.
// K in [BHkv][S][D]; V pre-transposed to [BHkv][D][S]. Register prefetch.
__global__ __launch_bounds__(256)
void flash_attn(const unsigned short* __restrict__ Q,
                const unsigned short* __restrict__ Kb,
                const unsigned short* __restrict__ VT,
                unsigned short* __restrict__ O) {
    __shared__ unsigned short Ks[64][136];    // [key][d], stride 68 words ≡ 4 mod 32
    __shared__ unsigned short Vt[128][72];    // [d][key], stride 36 words ≡ 4 mod 32
    __shared__ unsigned short Ps[4][16][72];  // per-wave P scratch, stride 36 words
    int tid = threadIdx.x;
    int lane = tid & 63, w = tid >> 6;
    int quad = lane >> 4, l16 = lane & 15;
    int qt = blockIdx.x, h = blockIdx.y, b = blockIdx.z;
    int qbase = qt * 64 + w * 16;

    const size_t qoff = ((size_t)(b * NH_ + h) * S_ + qbase + l16) * D_;
    v8bf aq[4];
    for (int kt = 0; kt < 4; ++kt) aq[kt] = *(const v8bf*)&Q[qoff + kt * 32 + quad * 8];

    const int hkv = h >> 2;                                  // GROUPS=4
    const size_t kvbase = (size_t)(b * NKV_ + hkv) * S_ * D_;
    const size_t vtbase = kvbase;                            // same extent, [D][S]

    // staging assignments (4 uint4 each for K and V^T per thread)
    int krow[4], kch[4], vrow[4], vch[4];
    for (int i = 0; i < 4; ++i) {
        int idx = tid + i * 256;
        krow[i] = idx >> 4; kch[i] = idx & 15;   // 64 rows x 16 chunks
        vrow[i] = idx >> 3; vch[i] = idx & 7;    // 128 rows x 8 chunks
    }

    v4f zero = {0.f, 0.f, 0.f, 0.f};
    v4f o[8];
    for (int i = 0; i < 8; ++i) o[i] = zero;
    float m_[4] = {-1e30f, -1e30f, -1e30f, -1e30f};
    float l_[4] = {0.f, 0.f, 0.f, 0.f};

    const int ntiles = qt + 1;
    // prefetch tile 0
    uint4 kpre[4], vpre[4];
    for (int i = 0; i < 4; ++i) {
        kpre[i] = *(const uint4*)&Kb[kvbase + (size_t)krow[i] * D_ + kch[i] * 8];
        vpre[i] = *(const uint4*)&VT[vtbase + (size_t)vrow[i] * S_ + vch[i] * 8];
    }

    for (int t = 0; t < ntiles; ++t) {
        int kv0 = t * 64;
        __syncthreads();                      // previous tile's readers done
        for (int i = 0; i < 4; ++i) {
            *(uint4*)&Ks[krow[i]][kch[i] * 8] = kpre[i];
            *(uint4*)&Vt[vrow[i]][vch[i] * 8] = vpre[i];
        }
        __syncthreads();
        if (t + 1 < ntiles) {                 // prefetch next tile (overlaps compute)
            int nkv0 = kv0 + 64;
            for (int i = 0; i < 4; ++i) {
                kpre[i] = *(const uint4*)&Kb[kvbase + (size_t)(nkv0 + krow[i]) * D_ + kch[i] * 8];
                vpre[i] = *(const uint4*)&VT[vtbase + (size_t)vrow[i] * S_ + nkv0 + vch[i] * 8];
            }
        }

        // S = Q K^T : 16 q-rows x 64 keys (4 key-16-groups)
        v4f sa[4];
        for (int kg = 0; kg < 4; ++kg) sa[kg] = zero;
        for (int kg = 0; kg < 4; ++kg)
            for (int kt = 0; kt < 4; ++kt) {
                v8bf bk = *(const v8bf*)&Ks[kg * 16 + l16][kt * 32 + quad * 8];
                sa[kg] = __builtin_amdgcn_mfma_f32_16x16x32_bf16(aq[kt], bk, sa[kg], 0, 0, 0);
            }

        const float scale = 0.08838834764831845f;  // 1/sqrt(128)
        const bool diag = (t == qt);
        float p[4][4], al[4];
        for (int r = 0; r < 4; ++r) {
            int qrow = qbase + quad * 4 + r;
            float s0 = sa[0][r] * scale, s1 = sa[1][r] * scale;
            float s2 = sa[2][r] * scale, s3 = sa[3][r] * scale;
            if (diag) {
                if (kv0      + l16 > qrow) s0 = -1e30f;
                if (kv0 + 16 + l16 > qrow) s1 = -1e30f;
                if (kv0 + 32 + l16 > qrow) s2 = -1e30f;
                if (kv0 + 48 + l16 > qrow) s3 = -1e30f;
            }
            float rm = fmaxf(fmaxf(s0, s1), fmaxf(s2, s3));
            rm = fmaxf(rm, __shfl_xor(rm, 1));
            rm = fmaxf(rm, __shfl_xor(rm, 2));
            rm = fmaxf(rm, __shfl_xor(rm, 4));
            rm = fmaxf(rm, __shfl_xor(rm, 8));
            float mn = fmaxf(m_[r], rm);
            al[r] = __expf(m_[r] - mn);
            float p0 = __expf(s0 - mn), p1 = __expf(s1 - mn);
            float p2 = __expf(s2 - mn), p3 = __expf(s3 - mn);
            p[0][r] = p0; p[1][r] = p1; p[2][r] = p2; p[3][r] = p3;
            float rs = (p0 + p1) + (p2 + p3);
            rs += __shfl_xor(rs, 1);
            rs += __shfl_xor(rs, 2);
            rs += __shfl_xor(rs, 4);
            rs += __shfl_xor(rs, 8);
            l_[r] = l_[r] * al[r] + rs;
            m_[r] = mn;
        }
        for (int i = 0; i < 8; ++i)
            for (int r = 0; r < 4; ++r) o[i][r] *= al[r];

        // P: C-layout -> A-layout via per-wave LDS scratch (same-wave ordering)
        for (int kg = 0; kg < 4; ++kg)
            for (int r = 0; r < 4; ++r)
                Ps[w][quad * 4 + r][kg * 16 + l16] = f2bf(p[kg][r]);
        v8bf pa0 = *(const v8bf*)&Ps[w][l16][quad * 8];
        v8bf pa1 = *(const v8bf*)&Ps[w][l16][32 + quad * 8];
        for (int n8 = 0; n8 < 8; ++n8) {
            v8bf bv0 = *(const v8bf*)&Vt[n8 * 16 + l16][quad * 8];
            v8bf bv1 = *(const v8bf*)&Vt[n8 * 16 + l16][32 + quad * 8];
            o[n8] = __builtin_amdgcn_mfma_f32_16x16x32_bf16(pa0, bv0, o[n8], 0, 0, 0);
            o[n8] = __builtin_amdgcn_mfma_f32_16x16x32_bf16(pa1, bv1, o[n8], 0, 0, 0);
        }
    }

    for (int n8 = 0; n8 < 8; ++n8)
        for (int r = 0; r < 4; ++r) {
            int qg = qbase + quad * 4 + r;
            float val = o[n8][r] / l_[r];
            O[((size_t)(b * S_ + qg)) * HID_ + h * D_ + n8 * 16 + l16] = f2bf(val);
        }
}

// ---------------- launcher ------------------------------------------------
extern "C" void kernel_launch(void* const* d_in, const int* in_sizes, int n_in,
                              void* d_out, int out_size, void* d_ws, size_t ws_size,
                              hipStream_t stream) {
    const float* hid  = (const float*)d_in[0];
    const float* Wq   = (const float*)d_in[1];
    const float* Wk   = (const float*)d_in[2];
    const float* Wv   = (const float*)d_in[3];
    const float* Wo   = (const float*)d_in[4];
    const float* cosc = (const float*)d_in[5];
    const float* sinc = (const float*)d_in[6];
    // d_in[7] position_ids == arange, d_in[8] attention_mask == causal: implicit

    unsigned short* ws    = (unsigned short*)d_ws;
    // element offsets (bf16 = 2B each)
    unsigned short* wqkvT = ws;                                    // [6144][4096]  50.33 MB
    unsigned short* qbuf  = ws + (size_t)NQKV_ * HID_;             // [2][32][2048][128] 33.55 MB
    unsigned short* kbuf  = qbuf + (size_t)B_ * NH_ * S_ * D_;     // 8.39 MB
    unsigned short* vbuf  = kbuf + (size_t)B_ * NKV_ * S_ * D_;    // 8.39 MB
    unsigned short* hidB  = vbuf + (size_t)B_ * NKV_ * S_ * D_;    // [4096][4096] 33.55 MB -> peak 134.3 MB
    unsigned short* attn  = ws;                                    // alias wqkvT (dead after gemm1)
    unsigned short* woT   = ws + (size_t)M_ * HID_;                // alias wqkvT tail
    unsigned short* vTbuf = hidB;                                  // alias hidB (dead after gemm1), needs 8.39 MB

    // 1. hidden fp32 -> bf16
    cvt_f32_bf16<<<(M_ * HID_ / 4 + 255) / 256, 256, 0, stream>>>(hid, hidB, M_ * HID_ / 4);
    // 2. W^T staging: Wq|Wk|Wv transposed + converted
    transpose_f32_bf16<<<dim3(64, 64), 256, 0, stream>>>(Wq, wqkvT, HID_, HID_);
    transpose_f32_bf16<<<dim3(16, 64), 256, 0, stream>>>(Wk, wqkvT + (size_t)HID_ * HID_, HID_, NKV_ * D_);
    transpose_f32_bf16<<<dim3(16, 64), 256, 0, stream>>>(Wv, wqkvT + (size_t)(HID_ + NKV_ * D_) * HID_, HID_, NKV_ * D_);
    // 3. fused QKV projection, scatter to per-head layouts
    gemm_bt<0><<<dim3(NQKV_ / 128, M_ / 128), 256, 0, stream>>>(
        hidB, wqkvT, HID_, HID_, HID_, qbuf, kbuf, vbuf, nullptr);
    // 4. RoPE (in-place) + V transpose (hidB now dead -> vTbuf)
    rope_kernel<<<(B_ * NH_ * S_ * 64) / 256, 256, 0, stream>>>(qbuf, cosc, sinc, B_ * NH_ * S_ * 64);
    rope_kernel<<<(B_ * NKV_ * S_ * 64) / 256, 256, 0, stream>>>(kbuf, cosc, sinc, B_ * NKV_ * S_ * 64);
    transpose_v<<<dim3(S_ / 64, D_ / 64, B_ * NKV_), 256, 0, stream>>>(vbuf, vTbuf);
    // 5. causal flash attention -> attn [b,s,h*d] bf16 (reuses wqkvT region)
    flash_attn<<<dim3(S_ / 64, NH_, B_), 256, 0, stream>>>(qbuf, kbuf, vTbuf, attn);
    // 6. O projection: transpose Wo, then GEMM -> fp32 out
    transpose_f32_bf16<<<dim3(64, 64), 256, 0, stream>>>(Wo, woT, HID_, HID_);
    gemm_bt<1><<<dim3(HID_ / 128, M_ / 128), 256, 0, stream>>>(
        attn, woT, HID_, HID_, HID_, nullptr, nullptr, nullptr, (float*)d_out);
}

// Round 4
// 1184.787 us; speedup vs baseline: 1.1533x; 1.1125x over previous
//
#include <hip/hip_runtime.h>

#define B_ 2
#define S_ 2048
#define HID_ 4096
#define NH_ 32
#define NKV_ 8
#define D_ 128
#define M_ (B_*S_)                  // 4096 rows of hidden
#define NQKV_ (HID_ + 2*NKV_*D_)    // 6144

typedef __bf16 v8bf __attribute__((ext_vector_type(8)));
typedef float  v4f  __attribute__((ext_vector_type(4)));
typedef float  v16f __attribute__((ext_vector_type(16)));

__device__ __forceinline__ unsigned short f2bf(float x) {
    unsigned u = __float_as_uint(x);
    u += 0x7FFFu + ((u >> 16) & 1u);   // RNE
    return (unsigned short)(u >> 16);
}
__device__ __forceinline__ float bf2f(unsigned short h) {
    return __uint_as_float(((unsigned)h) << 16);
}
__device__ __forceinline__ unsigned pack2bf(float a, float b) {
    return (unsigned)f2bf(a) | ((unsigned)f2bf(b) << 16);
}
__device__ __forceinline__ float exp2g(float x) {
    return __builtin_amdgcn_exp2f(x);  // v_exp_f32: 2^x (avoids libm macro clash)
}

// async global->LDS, 16B per lane. LDS dest must be WAVE-UNIFORM base;
// HW writes base + lane*16. Global address is per-lane.
__device__ __forceinline__ void gl_lds16(const unsigned short* g, unsigned short* l) {
    __builtin_amdgcn_global_load_lds(
        (const __attribute__((address_space(1))) void*)g,
        (__attribute__((address_space(3))) void*)l, 16, 0, 0);
}

// ---------------- fp32 -> bf16 elementwise convert (x4 vectorized) ---------
__global__ __launch_bounds__(256)
void cvt_f32_bf16(const float* __restrict__ src, unsigned short* __restrict__ dst, int n4) {
    int i = blockIdx.x * 256 + threadIdx.x;
    if (i >= n4) return;
    float4 v = ((const float4*)src)[i];
    ushort4 o;
    o.x = f2bf(v.x); o.y = f2bf(v.y); o.z = f2bf(v.z); o.w = f2bf(v.w);
    ((ushort4*)dst)[i] = o;
}

// ------------- transpose+convert: dst[n][k] = bf16(src[k][n]), fp32 src ----
__global__ __launch_bounds__(256)
void transpose_f32_bf16(const float* __restrict__ src,
                        unsigned short* __restrict__ dst, int K, int N) {
    __shared__ unsigned short tile[64][65];
    int n0 = blockIdx.x * 64, k0 = blockIdx.y * 64;
    int tid = threadIdx.x;
    for (int i = 0; i < 16; ++i) {
        int fi = tid + i * 256;
        int r = fi >> 6, c = fi & 63;
        tile[r][c] = f2bf(src[(size_t)(k0 + r) * N + n0 + c]);
    }
    __syncthreads();
    for (int i = 0; i < 16; ++i) {
        int fi = tid + i * 256;
        int r = fi >> 6, c = fi & 63;
        dst[(size_t)(n0 + r) * K + k0 + c] = tile[c][r];
    }
}

// ------------- per-head V transpose: [BHkv][S][D] -> [BHkv][D][S] bf16 -----
__global__ __launch_bounds__(256)
void transpose_v(const unsigned short* __restrict__ src,
                 unsigned short* __restrict__ dst) {
    __shared__ unsigned short tile[64][65];
    int s0 = blockIdx.x * 64, d0 = blockIdx.y * 64;
    size_t base = (size_t)blockIdx.z * S_ * D_;
    int tid = threadIdx.x;
    for (int i = 0; i < 16; ++i) {
        int fi = tid + i * 256;
        int r = fi >> 6, c = fi & 63;            // r: s-offset, c: d-offset
        tile[r][c] = src[base + (size_t)(s0 + r) * D_ + d0 + c];
    }
    __syncthreads();
    for (int i = 0; i < 16; ++i) {
        int fi = tid + i * 256;
        int r = fi >> 6, c = fi & 63;            // r: d-offset, c: s-offset
        dst[base + (size_t)(d0 + r) * S_ + s0 + c] = tile[c][r];
    }
}

// ---------------- GEMM: C[M][N] = A[M][K] * BT[N][K]^T  (bf16 in, fp32 acc) -
// m97 structure: global_load_lds width-16 staging into LINEAR (unpadded) LDS.
template <int MODE>
__global__ __launch_bounds__(256)
void gemm_bt(const unsigned short* __restrict__ A,
             const unsigned short* __restrict__ BT,
             int K, int lda, int ldb,
             unsigned short* __restrict__ outQ,
             unsigned short* __restrict__ outK,
             unsigned short* __restrict__ outV,
             float* __restrict__ outF) {
    __shared__ unsigned short As[128][32];   // linear: gl_lds dest is base+lane*16
    __shared__ unsigned short Bs[128][32];
    int tid = threadIdx.x;
    int lane = tid & 63, wid = tid >> 6;
    int quad = lane >> 4, l16 = lane & 15;
    int wr = wid >> 1, wc = wid & 1;
    int r0 = blockIdx.y * 128, n0 = blockIdx.x * 128;

    v4f zero = {0.f, 0.f, 0.f, 0.f};
    v4f acc[4][4];
    for (int i = 0; i < 4; ++i) for (int j = 0; j < 4; ++j) acc[i][j] = zero;

    const int srow = wid * 32 + (lane >> 2);      // per-lane source row within tile
    const int sch  = (lane & 3) * 8;              // 16B chunk (8 shorts)
    const unsigned short* gA = &A [(size_t)(r0 + srow) * lda + sch];
    const unsigned short* gB = &BT[(size_t)(n0 + srow) * ldb + sch];
    unsigned short* lA0 = &As[wid * 32][0];
    unsigned short* lA1 = &As[wid * 32 + 16][0];
    unsigned short* lB0 = &Bs[wid * 32][0];
    unsigned short* lB1 = &Bs[wid * 32 + 16][0];

    for (int kt = 0; kt < K / 32; ++kt) {
        int kk = kt * 32;
        gl_lds16(gA + kk, lA0);
        gl_lds16(gA + (size_t)16 * lda + kk, lA1);
        gl_lds16(gB + kk, lB0);
        gl_lds16(gB + (size_t)16 * ldb + kk, lB1);
        __syncthreads();
        v8bf av[4], bv[4];
        for (int ms = 0; ms < 4; ++ms) av[ms] = *(const v8bf*)&As[wr * 64 + ms * 16 + l16][quad * 8];
        for (int ns = 0; ns < 4; ++ns) bv[ns] = *(const v8bf*)&Bs[wc * 64 + ns * 16 + l16][quad * 8];
        for (int ms = 0; ms < 4; ++ms)
            for (int ns = 0; ns < 4; ++ns)
                acc[ms][ns] = __builtin_amdgcn_mfma_f32_16x16x32_bf16(av[ms], bv[ns], acc[ms][ns], 0, 0, 0);
        __syncthreads();
    }

    for (int ms = 0; ms < 4; ++ms)
        for (int ns = 0; ns < 4; ++ns)
            for (int r = 0; r < 4; ++r) {
                int row = r0 + wr * 64 + ms * 16 + quad * 4 + r;   // C row = quad*4+reg (m89)
                int col = n0 + wc * 64 + ns * 16 + l16;            // C col = lane&15
                if (MODE == 1) {
                    outF[(size_t)row * HID_ + col] = acc[ms][ns][r];
                } else {
                    unsigned short hv = f2bf(acc[ms][ns][r]);
                    int b = row >> 11, s = row & (S_ - 1);
                    if (col < HID_) {
                        int h = col >> 7, d = col & 127;
                        outQ[((size_t)((b * NH_ + h) * S_ + s)) * D_ + d] = hv;
                    } else if (col < HID_ + NKV_ * D_) {
                        int j = col - HID_; int h = j >> 7, d = j & 127;
                        outK[((size_t)((b * NKV_ + h) * S_ + s)) * D_ + d] = hv;
                    } else {
                        int j = col - HID_ - NKV_ * D_; int h = j >> 7, d = j & 127;
                        outV[((size_t)((b * NKV_ + h) * S_ + s)) * D_ + d] = hv;
                    }
                }
            }
}

// ---------------- RoPE in-place on [BH][S][D] bf16, fp32 cos/sin ----------
__global__ __launch_bounds__(256)
void rope_kernel(unsigned short* __restrict__ buf,
                 const float* __restrict__ cosc,
                 const float* __restrict__ sinc, int total) {
    int idx = blockIdx.x * 256 + threadIdx.x;
    if (idx >= total) return;
    int d2 = idx & 63;
    int s  = (idx >> 6) & (S_ - 1);
    int bh = idx >> 17;                       // /(64*2048)
    size_t base = ((size_t)bh * S_ + s) * D_;
    float c  = cosc[s * D_ + d2];             // cos[s][d2] == cos[s][d2+64]
    float sn = sinc[s * D_ + d2];
    float x1 = bf2f(buf[base + d2]);
    float x2 = bf2f(buf[base + d2 + 64]);
    buf[base + d2]      = f2bf(x1 * c - x2 * sn);
    buf[base + d2 + 64] = f2bf(x2 * c + x1 * sn);
}

// ---------------- causal flash attention v3 (m214-style) -------------------
// grid: (16, NH, B) with qt = 15-bx (LPT). block: 256 = 4 waves x 32 q-rows.
// 32x32x16 MFMA. Swapped QK^T: mfma(K,Q) -> S^T with q = lane&31 (softmax
// lane-local). Swapped PV: mfma(V^T,P) -> O with q = lane&31 (rescale
// lane-local). P stays in registers via bf16-pack + shfl_xor(32) exchange.
// K tile [64][128] in LDS, XOR-swizzled (chunk ^= row&7) on write and read.
// V^T tile [128][72] (pad => 4-way residual conflict, acceptable).
__global__ __launch_bounds__(256)
void flash_attn(const unsigned short* __restrict__ Q,
                const unsigned short* __restrict__ Kb,
                const unsigned short* __restrict__ VT,
                unsigned short* __restrict__ O) {
    __shared__ unsigned short Ks[64 * 128];   // swizzled, no pad
    __shared__ unsigned short Vt[128][72];
    int tid = threadIdx.x;
    int lane = tid & 63, w = tid >> 6;
    int l31 = lane & 31, hi = lane >> 5;
    int qt = 15 - (int)blockIdx.x;            // long blocks first (LPT)
    int h = blockIdx.y, b = blockIdx.z;
    int qbase = qt * 128 + w * 32;

    // Q B-fragments: n = q = qbase+l31, k = kt*16 + hi*8 + j  (8 frags, d=128)
    const size_t qoff = ((size_t)(b * NH_ + h) * S_ + qbase + l31) * D_ + hi * 8;
    v8bf aq[8];
    #pragma unroll
    for (int kt = 0; kt < 8; ++kt) aq[kt] = *(const v8bf*)&Q[qoff + kt * 16];

    const int hkv = h >> 2;                                  // GROUPS=4
    const size_t kvbase = (size_t)(b * NKV_ + hkv) * S_ * D_;
    const size_t vtbase = kvbase;                            // [D][S] extent

    // staging: K = 64 rows x 16 chunks, V = 128 rows x 8 chunks (16B chunks)
    int krow[4], kch[4], vrow[4], vch[4];
    #pragma unroll
    for (int i = 0; i < 4; ++i) {
        int idx = tid + i * 256;
        krow[i] = idx >> 4; kch[i] = idx & 15;
        vrow[i] = idx >> 3; vch[i] = idx & 7;
    }

    v16f o[4];
    #pragma unroll
    for (int n = 0; n < 4; ++n)
        #pragma unroll
        for (int r = 0; r < 16; ++r) o[n][r] = 0.f;
    float m2 = -1e30f, l_ = 0.f;              // running max/denom, exp2 domain

    const int ntB = 2 * qt + 2;               // block-level KV tiles
    const int twmax = (qbase + 31) >> 6;      // last tile this wave computes

    uint4 kpre[4], vpre[4];
    #pragma unroll
    for (int i = 0; i < 4; ++i) {
        kpre[i] = *(const uint4*)&Kb[kvbase + (size_t)krow[i] * D_ + kch[i] * 8];
        vpre[i] = *(const uint4*)&VT[vtbase + (size_t)vrow[i] * S_ + vch[i] * 8];
    }

    for (int t = 0; t < ntB; ++t) {
        int kv0 = t * 64;
        __syncthreads();                      // previous tile's readers done
        #pragma unroll
        for (int i = 0; i < 4; ++i) {
            // K write-side swizzle: chunk ^= (row&7)
            *(uint4*)&Ks[(size_t)krow[i] * 128 + ((kch[i] * 8) ^ ((krow[i] & 7) << 3))] = kpre[i];
            *(uint4*)&Vt[vrow[i]][vch[i] * 8] = vpre[i];
        }
        __syncthreads();
        if (t + 1 < ntB) {                    // prefetch next tile
            int nkv0 = kv0 + 64;
            #pragma unroll
            for (int i = 0; i < 4; ++i) {
                kpre[i] = *(const uint4*)&Kb[kvbase + (size_t)(nkv0 + krow[i]) * D_ + kch[i] * 8];
                vpre[i] = *(const uint4*)&VT[vtbase + (size_t)vrow[i] * S_ + nkv0 + vch[i] * 8];
            }
        }
        if (t > twmax) continue;              // fully-masked tile: barriers done

        // QK^T (swapped): S^T[key][q], key = kv0 + kb32*32 + (r&3)+8*(r>>2)+4*hi
        v16f s0, s1;
        #pragma unroll
        for (int r = 0; r < 16; ++r) { s0[r] = 0.f; s1[r] = 0.f; }
        #pragma unroll
        for (int kt = 0; kt < 8; ++kt) {
            int cw = (kt * 16 + hi * 8) ^ ((l31 & 7) << 3);   // read-side swizzle
            v8bf k0 = *(const v8bf*)&Ks[(size_t)l31 * 128 + cw];
            v8bf k1 = *(const v8bf*)&Ks[(size_t)(32 + l31) * 128 + cw];
            s0 = __builtin_amdgcn_mfma_f32_32x32x16_bf16(k0, aq[kt], s0, 0, 0, 0);
            s1 = __builtin_amdgcn_mfma_f32_32x32x16_bf16(k1, aq[kt], s1, 0, 0, 0);
        }

        if (kv0 + 63 > qbase) {               // diagonal tile: causal mask
            int vq = qbase + l31 - kv0 - 4 * hi;
            #pragma unroll
            for (int r = 0; r < 16; ++r) {
                int c0 = (r & 3) + 8 * (r >> 2);
                if (c0 > vq)      s0[r] = -1e30f;
                if (c0 + 32 > vq) s1[r] = -1e30f;
            }
        }
        // row max: 32 in-reg values + cross-half exchange (q is lane-local)
        float rm = fmaxf(s0[0], s1[0]);
        #pragma unroll
        for (int r = 1; r < 16; ++r) rm = fmaxf(rm, fmaxf(s0[r], s1[r]));
        rm = fmaxf(rm, __shfl_xor(rm, 32));
        const float cexp = 0.1275279431f;     // log2(e)/sqrt(128)
        float m2n = fmaxf(m2, rm * cexp);
        float al = exp2g(m2 - m2n);
        float rs = 0.f;
        #pragma unroll
        for (int r = 0; r < 16; ++r) {
            s0[r] = exp2g(__builtin_fmaf(s0[r], cexp, -m2n));
            s1[r] = exp2g(__builtin_fmaf(s1[r], cexp, -m2n));
            rs += s0[r] + s1[r];
        }
        rs += __shfl_xor(rs, 32);
        l_ = l_ * al + rs;
        m2 = m2n;
        #pragma unroll
        for (int n = 0; n < 4; ++n)
            #pragma unroll
            for (int r = 0; r < 16; ++r) o[n][r] *= al;

        // pack P (f32 -> bf16 u32 pairs), group g holds keys 8g+4hi+{0..3}
        unsigned pk0[4][2], pk1[4][2];
        #pragma unroll
        for (int g = 0; g < 4; ++g) {
            pk0[g][0] = pack2bf(s0[4*g],   s0[4*g+1]);
            pk0[g][1] = pack2bf(s0[4*g+2], s0[4*g+3]);
            pk1[g][0] = pack2bf(s1[4*g],   s1[4*g+1]);
            pk1[g][1] = pack2bf(s1[4*g+2], s1[4*g+3]);
        }
        const bool hb = (hi != 0);
        // PV (swapped): per 16-key block kb, B-frag = P[q=l31][kb*16+hi*8+j].
        // Element j: holder lane-half = j>>2, holder reg group = (kb&1)*2+hi.
        #pragma unroll
        for (int kb = 0; kb < 4; ++kb) {
            const int g0 = (kb & 1) * 2;
            unsigned la, lb, oa, ob;
            if (kb < 2) { la = pk0[g0][0]; lb = pk0[g0][1]; oa = pk0[g0+1][0]; ob = pk0[g0+1][1]; }
            else        { la = pk1[g0][0]; lb = pk1[g0][1]; oa = pk1[g0+1][0]; ob = pk1[g0+1][1]; }
            unsigned sa0 = hb ? la : oa, sa1 = hb ? lb : ob;       // send grp g0+(1-hi)
            unsigned ra0 = (unsigned)__shfl_xor((int)sa0, 32);     // recv partner grp g0+hi
            unsigned ra1 = (unsigned)__shfl_xor((int)sa1, 32);
            unsigned ma0 = hb ? oa : la, ma1 = hb ? ob : lb;       // my grp g0+hi
            union { unsigned u[4]; v8bf v; } pf;
            pf.u[0] = hb ? ra0 : ma0; pf.u[1] = hb ? ra1 : ma1;    // j=0..3 (half 0)
            pf.u[2] = hb ? ma0 : ra0; pf.u[3] = hb ? ma1 : ra1;    // j=4..7 (half 1)
            #pragma unroll
            for (int n = 0; n < 4; ++n) {
                v8bf av = *(const v8bf*)&Vt[n * 32 + l31][kb * 16 + hi * 8];
                o[n] = __builtin_amdgcn_mfma_f32_32x32x16_bf16(av, pf.v, o[n], 0, 0, 0);
            }
        }
    }

    // epilogue: O[d][q] layout -> lane owns q = qbase+l31, d = n*32+(r&3)+8*(r>>2)+4*hi
    float inv = 1.0f / l_;
    int q = qbase + l31;
    size_t obase = ((size_t)(b * S_ + q)) * HID_ + h * D_;
    #pragma unroll
    for (int n = 0; n < 4; ++n)
        #pragma unroll
        for (int rg = 0; rg < 4; ++rg) {
            ushort4 st;
            st.x = f2bf(o[n][4*rg+0] * inv);
            st.y = f2bf(o[n][4*rg+1] * inv);
            st.z = f2bf(o[n][4*rg+2] * inv);
            st.w = f2bf(o[n][4*rg+3] * inv);
            *(ushort4*)&O[obase + n * 32 + 8 * rg + 4 * hi] = st;
        }
}

// ---------------- launcher ------------------------------------------------
extern "C" void kernel_launch(void* const* d_in, const int* in_sizes, int n_in,
                              void* d_out, int out_size, void* d_ws, size_t ws_size,
                              hipStream_t stream) {
    const float* hid  = (const float*)d_in[0];
    const float* Wq   = (const float*)d_in[1];
    const float* Wk   = (const float*)d_in[2];
    const float* Wv   = (const float*)d_in[3];
    const float* Wo   = (const float*)d_in[4];
    const float* cosc = (const float*)d_in[5];
    const float* sinc = (const float*)d_in[6];

    unsigned short* ws    = (unsigned short*)d_ws;
    unsigned short* wqkvT = ws;                                    // [6144][4096]
    unsigned short* qbuf  = ws + (size_t)NQKV_ * HID_;
    unsigned short* kbuf  = qbuf + (size_t)B_ * NH_ * S_ * D_;
    unsigned short* vbuf  = kbuf + (size_t)B_ * NKV_ * S_ * D_;
    unsigned short* hidB  = vbuf + (size_t)B_ * NKV_ * S_ * D_;
    unsigned short* attn  = ws;                                    // alias wqkvT
    unsigned short* woT   = ws + (size_t)M_ * HID_;                // alias tail
    unsigned short* vTbuf = hidB;                                  // alias hidB

    // 1. hidden fp32 -> bf16
    cvt_f32_bf16<<<(M_ * HID_ / 4 + 255) / 256, 256, 0, stream>>>(hid, hidB, M_ * HID_ / 4);
    // 2. W^T staging
    transpose_f32_bf16<<<dim3(64, 64), 256, 0, stream>>>(Wq, wqkvT, HID_, HID_);
    transpose_f32_bf16<<<dim3(16, 64), 256, 0, stream>>>(Wk, wqkvT + (size_t)HID_ * HID_, HID_, NKV_ * D_);
    transpose_f32_bf16<<<dim3(16, 64), 256, 0, stream>>>(Wv, wqkvT + (size_t)(HID_ + NKV_ * D_) * HID_, HID_, NKV_ * D_);
    // 3. fused QKV projection, scatter to per-head layouts
    gemm_bt<0><<<dim3(NQKV_ / 128, M_ / 128), 256, 0, stream>>>(
        hidB, wqkvT, HID_, HID_, HID_, qbuf, kbuf, vbuf, nullptr);
    // 4. RoPE (in-place) + V transpose
    rope_kernel<<<(B_ * NH_ * S_ * 64) / 256, 256, 0, stream>>>(qbuf, cosc, sinc, B_ * NH_ * S_ * 64);
    rope_kernel<<<(B_ * NKV_ * S_ * 64) / 256, 256, 0, stream>>>(kbuf, cosc, sinc, B_ * NKV_ * S_ * 64);
    transpose_v<<<dim3(S_ / 64, D_ / 64, B_ * NKV_), 256, 0, stream>>>(vbuf, vTbuf);
    // 5. causal flash attention v3 -> attn [b,s,h*d] bf16
    flash_attn<<<dim3(16, NH_, B_), 256, 0, stream>>>(qbuf, kbuf, vTbuf, attn);
    // 6. O projection
    transpose_f32_bf16<<<dim3(64, 64), 256, 0, stream>>>(Wo, woT, HID_, HID_);
    gemm_bt<1><<<dim3(HID_ / 128, M_ / 128), 256, 0, stream>>>(
        attn, woT, HID_, HID_, HID_, nullptr, nullptr, nullptr, (float*)d_out);
}

// Round 5
// 1070.429 us; speedup vs baseline: 1.2765x; 1.1068x over previous
//
#include <hip/hip_runtime.h>

#define B_ 2
#define S_ 2048
#define HID_ 4096
#define NH_ 32
#define NKV_ 8
#define D_ 128
#define M_ (B_*S_)                  // 4096 rows of hidden
#define NQKV_ (HID_ + 2*NKV_*D_)    // 6144

typedef __bf16 v8bf __attribute__((ext_vector_type(8)));
typedef float  v4f  __attribute__((ext_vector_type(4)));
typedef float  v16f __attribute__((ext_vector_type(16)));

__device__ __forceinline__ unsigned short f2bf(float x) {
    unsigned u = __float_as_uint(x);
    u += 0x7FFFu + ((u >> 16) & 1u);   // RNE
    return (unsigned short)(u >> 16);
}
__device__ __forceinline__ float bf2f(unsigned short h) {
    return __uint_as_float(((unsigned)h) << 16);
}
__device__ __forceinline__ unsigned pack2bf(float a, float b) {
    return (unsigned)f2bf(a) | ((unsigned)f2bf(b) << 16);
}
__device__ __forceinline__ float exp2g(float x) {
    return __builtin_amdgcn_exp2f(x);  // v_exp_f32: 2^x (avoids libm macro clash)
}

// async global->LDS, 16B per lane. LDS dest must be WAVE-UNIFORM base;
// HW writes base + lane*16. Global address is per-lane.
__device__ __forceinline__ void gl_lds16(const unsigned short* g, unsigned short* l) {
    __builtin_amdgcn_global_load_lds(
        (const __attribute__((address_space(1))) void*)g,
        (__attribute__((address_space(3))) void*)l, 16, 0, 0);
}

// ---------------- fp32 -> bf16 elementwise convert (x4 vectorized) ---------
__global__ __launch_bounds__(256)
void cvt_f32_bf16(const float* __restrict__ src, unsigned short* __restrict__ dst, int n4) {
    int i = blockIdx.x * 256 + threadIdx.x;
    if (i >= n4) return;
    float4 v = ((const float4*)src)[i];
    ushort4 o;
    o.x = f2bf(v.x); o.y = f2bf(v.y); o.z = f2bf(v.z); o.w = f2bf(v.w);
    ((ushort4*)dst)[i] = o;
}

// ------------- transpose+convert: dst[n][k] = bf16(src[k][n]), fp32 src ----
__global__ __launch_bounds__(256)
void transpose_f32_bf16(const float* __restrict__ src,
                        unsigned short* __restrict__ dst, int K, int N) {
    __shared__ unsigned short tile[64][65];
    int n0 = blockIdx.x * 64, k0 = blockIdx.y * 64;
    int tid = threadIdx.x;
    for (int i = 0; i < 16; ++i) {
        int fi = tid + i * 256;
        int r = fi >> 6, c = fi & 63;
        tile[r][c] = f2bf(src[(size_t)(k0 + r) * N + n0 + c]);
    }
    __syncthreads();
    for (int i = 0; i < 16; ++i) {
        int fi = tid + i * 256;
        int r = fi >> 6, c = fi & 63;
        dst[(size_t)(n0 + r) * K + k0 + c] = tile[c][r];
    }
}

// ------------- per-head V transpose: [BHkv][S][D] -> [BHkv][D][S] bf16 -----
__global__ __launch_bounds__(256)
void transpose_v(const unsigned short* __restrict__ src,
                 unsigned short* __restrict__ dst) {
    __shared__ unsigned short tile[64][65];
    int s0 = blockIdx.x * 64, d0 = blockIdx.y * 64;
    size_t base = (size_t)blockIdx.z * S_ * D_;
    int tid = threadIdx.x;
    for (int i = 0; i < 16; ++i) {
        int fi = tid + i * 256;
        int r = fi >> 6, c = fi & 63;            // r: s-offset, c: d-offset
        tile[r][c] = src[base + (size_t)(s0 + r) * D_ + d0 + c];
    }
    __syncthreads();
    for (int i = 0; i < 16; ++i) {
        int fi = tid + i * 256;
        int r = fi >> 6, c = fi & 63;            // r: d-offset, c: s-offset
        dst[base + (size_t)(d0 + r) * S_ + s0 + c] = tile[c][r];
    }
}

// ---------------- GEMM: C[M][N] = A[M][K] * BT[N][K]^T  (bf16 in, fp32 acc) -
// m97 structure: global_load_lds width-16 staging into LINEAR (unpadded) LDS.
template <int MODE>
__global__ __launch_bounds__(256)
void gemm_bt(const unsigned short* __restrict__ A,
             const unsigned short* __restrict__ BT,
             int K, int lda, int ldb,
             unsigned short* __restrict__ outQ,
             unsigned short* __restrict__ outK,
             unsigned short* __restrict__ outV,
             float* __restrict__ outF) {
    __shared__ unsigned short As[128][32];   // linear: gl_lds dest is base+lane*16
    __shared__ unsigned short Bs[128][32];
    int tid = threadIdx.x;
    int lane = tid & 63, wid = tid >> 6;
    int quad = lane >> 4, l16 = lane & 15;
    int wr = wid >> 1, wc = wid & 1;
    int r0 = blockIdx.y * 128, n0 = blockIdx.x * 128;

    v4f zero = {0.f, 0.f, 0.f, 0.f};
    v4f acc[4][4];
    for (int i = 0; i < 4; ++i) for (int j = 0; j < 4; ++j) acc[i][j] = zero;

    const int srow = wid * 32 + (lane >> 2);      // per-lane source row within tile
    const int sch  = (lane & 3) * 8;              // 16B chunk (8 shorts)
    const unsigned short* gA = &A [(size_t)(r0 + srow) * lda + sch];
    const unsigned short* gB = &BT[(size_t)(n0 + srow) * ldb + sch];
    unsigned short* lA0 = &As[wid * 32][0];
    unsigned short* lA1 = &As[wid * 32 + 16][0];
    unsigned short* lB0 = &Bs[wid * 32][0];
    unsigned short* lB1 = &Bs[wid * 32 + 16][0];

    for (int kt = 0; kt < K / 32; ++kt) {
        int kk = kt * 32;
        gl_lds16(gA + kk, lA0);
        gl_lds16(gA + (size_t)16 * lda + kk, lA1);
        gl_lds16(gB + kk, lB0);
        gl_lds16(gB + (size_t)16 * ldb + kk, lB1);
        __syncthreads();
        v8bf av[4], bv[4];
        for (int ms = 0; ms < 4; ++ms) av[ms] = *(const v8bf*)&As[wr * 64 + ms * 16 + l16][quad * 8];
        for (int ns = 0; ns < 4; ++ns) bv[ns] = *(const v8bf*)&Bs[wc * 64 + ns * 16 + l16][quad * 8];
        for (int ms = 0; ms < 4; ++ms)
            for (int ns = 0; ns < 4; ++ns)
                acc[ms][ns] = __builtin_amdgcn_mfma_f32_16x16x32_bf16(av[ms], bv[ns], acc[ms][ns], 0, 0, 0);
        __syncthreads();
    }

    for (int ms = 0; ms < 4; ++ms)
        for (int ns = 0; ns < 4; ++ns)
            for (int r = 0; r < 4; ++r) {
                int row = r0 + wr * 64 + ms * 16 + quad * 4 + r;   // C row = quad*4+reg (m89)
                int col = n0 + wc * 64 + ns * 16 + l16;            // C col = lane&15
                if (MODE == 1) {
                    outF[(size_t)row * HID_ + col] = acc[ms][ns][r];
                } else {
                    unsigned short hv = f2bf(acc[ms][ns][r]);
                    int b = row >> 11, s = row & (S_ - 1);
                    if (col < HID_) {
                        int h = col >> 7, d = col & 127;
                        outQ[((size_t)((b * NH_ + h) * S_ + s)) * D_ + d] = hv;
                    } else if (col < HID_ + NKV_ * D_) {
                        int j = col - HID_; int h = j >> 7, d = j & 127;
                        outK[((size_t)((b * NKV_ + h) * S_ + s)) * D_ + d] = hv;
                    } else {
                        int j = col - HID_ - NKV_ * D_; int h = j >> 7, d = j & 127;
                        outV[((size_t)((b * NKV_ + h) * S_ + s)) * D_ + d] = hv;
                    }
                }
            }
}

// ---------------- RoPE in-place on [BH][S][D] bf16, fp32 cos/sin ----------
__global__ __launch_bounds__(256)
void rope_kernel(unsigned short* __restrict__ buf,
                 const float* __restrict__ cosc,
                 const float* __restrict__ sinc, int total) {
    int idx = blockIdx.x * 256 + threadIdx.x;
    if (idx >= total) return;
    int d2 = idx & 63;
    int s  = (idx >> 6) & (S_ - 1);
    int bh = idx >> 17;                       // /(64*2048)
    size_t base = ((size_t)bh * S_ + s) * D_;
    float c  = cosc[s * D_ + d2];             // cos[s][d2] == cos[s][d2+64]
    float sn = sinc[s * D_ + d2];
    float x1 = bf2f(buf[base + d2]);
    float x2 = bf2f(buf[base + d2 + 64]);
    buf[base + d2]      = f2bf(x1 * c - x2 * sn);
    buf[base + d2 + 64] = f2bf(x2 * c + x1 * sn);
}

// ---------------- causal flash attention v4 (paired q-tiles) ---------------
// grid: (8, NH, B). block: 256 = 4 waves x 32 q-rows. Each block runs TWO
// q-tiles: qt = 15-p then qt = p  => per-block work = 34 KV tiles, identical
// for every block (perfect static balance; fixes the qt-aliasing imbalance
// where CU i received 4 blocks of identical qt). 32x32x16 MFMA, swapped
// QK^T / PV, in-register P. K and V^T tiles both linear with XOR-chunk
// swizzle (chunk ^= row&7).
__global__ __launch_bounds__(256)
void flash_attn(const unsigned short* __restrict__ Q,
                const unsigned short* __restrict__ Kb,
                const unsigned short* __restrict__ VT,
                unsigned short* __restrict__ O) {
    __shared__ unsigned short Ks[64 * 128];   // [key][d], swizzled
    __shared__ unsigned short Vt[128 * 64];   // [d][key], swizzled
    int tid = threadIdx.x;
    int lane = tid & 63, w = tid >> 6;
    int l31 = lane & 31, hi = lane >> 5;
    int p = blockIdx.x;                       // 0..7
    int h = blockIdx.y, b = blockIdx.z;

    const int hkv = h >> 2;                                  // GROUPS=4
    const size_t kvbase = (size_t)(b * NKV_ + hkv) * S_ * D_;
    const size_t vtbase = kvbase;                            // [D][S] extent

    // staging: K = 64 rows x 16 chunks, V = 128 rows x 8 chunks (16B chunks)
    int krow[4], kch[4], vrow[4], vch[4];
    #pragma unroll
    for (int i = 0; i < 4; ++i) {
        int idx = tid + i * 256;
        krow[i] = idx >> 4; kch[i] = idx & 15;
        vrow[i] = idx >> 3; vch[i] = idx & 7;
    }
    const int vsw = (l31 & 7) << 3;           // read-side V swizzle (row&7, n*32 ≡ 0 mod 8)

    for (int ph = 0; ph < 2; ++ph) {
        const int qt = ph == 0 ? 15 - p : p;  // long tile first
        const int qbase = qt * 128 + w * 32;

        // Q B-fragments: n = q = qbase+l31, k = kt*16 + hi*8 + j
        const size_t qoff = ((size_t)(b * NH_ + h) * S_ + qbase + l31) * D_ + hi * 8;
        v8bf aq[8];
        #pragma unroll
        for (int kt = 0; kt < 8; ++kt) aq[kt] = *(const v8bf*)&Q[qoff + kt * 16];

        v16f o[4];
        #pragma unroll
        for (int n = 0; n < 4; ++n)
            #pragma unroll
            for (int r = 0; r < 16; ++r) o[n][r] = 0.f;
        float m2 = -1e30f, l_ = 0.f;          // running max/denom, exp2 domain

        const int ntB = 2 * qt + 2;           // block-level KV tiles
        const int twmax = (qbase + 31) >> 6;  // last tile this wave computes

        uint4 kpre[4], vpre[4];
        #pragma unroll
        for (int i = 0; i < 4; ++i) {
            kpre[i] = *(const uint4*)&Kb[kvbase + (size_t)krow[i] * D_ + kch[i] * 8];
            vpre[i] = *(const uint4*)&VT[vtbase + (size_t)vrow[i] * S_ + vch[i] * 8];
        }

        for (int t = 0; t < ntB; ++t) {
            int kv0 = t * 64;
            __syncthreads();                  // previous tile's readers done
            #pragma unroll
            for (int i = 0; i < 4; ++i) {
                *(uint4*)&Ks[(size_t)krow[i] * 128 + ((kch[i] * 8) ^ ((krow[i] & 7) << 3))] = kpre[i];
                *(uint4*)&Vt[(size_t)vrow[i] * 64 + ((vch[i] * 8) ^ ((vrow[i] & 7) << 3))] = vpre[i];
            }
            __syncthreads();
            if (t + 1 < ntB) {                // prefetch next tile
                int nkv0 = kv0 + 64;
                #pragma unroll
                for (int i = 0; i < 4; ++i) {
                    kpre[i] = *(const uint4*)&Kb[kvbase + (size_t)(nkv0 + krow[i]) * D_ + kch[i] * 8];
                    vpre[i] = *(const uint4*)&VT[vtbase + (size_t)vrow[i] * S_ + nkv0 + vch[i] * 8];
                }
            }
            if (t > twmax) continue;          // fully-masked tile: barriers done

            // QK^T (swapped): S^T[key][q], key = kv0 + kb32*32 + (r&3)+8*(r>>2)+4*hi
            v16f s0, s1;
            #pragma unroll
            for (int r = 0; r < 16; ++r) { s0[r] = 0.f; s1[r] = 0.f; }
            #pragma unroll
            for (int kt = 0; kt < 8; ++kt) {
                int cw = (kt * 16 + hi * 8) ^ ((l31 & 7) << 3);   // read-side swizzle
                v8bf k0 = *(const v8bf*)&Ks[(size_t)l31 * 128 + cw];
                v8bf k1 = *(const v8bf*)&Ks[(size_t)(32 + l31) * 128 + cw];
                s0 = __builtin_amdgcn_mfma_f32_32x32x16_bf16(k0, aq[kt], s0, 0, 0, 0);
                s1 = __builtin_amdgcn_mfma_f32_32x32x16_bf16(k1, aq[kt], s1, 0, 0, 0);
            }

            if (kv0 + 63 > qbase) {           // diagonal tile: causal mask
                int vq = qbase + l31 - kv0 - 4 * hi;
                #pragma unroll
                for (int r = 0; r < 16; ++r) {
                    int c0 = (r & 3) + 8 * (r >> 2);
                    if (c0 > vq)      s0[r] = -1e30f;
                    if (c0 + 32 > vq) s1[r] = -1e30f;
                }
            }
            // row max: 32 in-reg values + cross-half exchange (q is lane-local)
            float rm = fmaxf(s0[0], s1[0]);
            #pragma unroll
            for (int r = 1; r < 16; ++r) rm = fmaxf(rm, fmaxf(s0[r], s1[r]));
            rm = fmaxf(rm, __shfl_xor(rm, 32));
            const float cexp = 0.1275279431f; // log2(e)/sqrt(128)
            float m2n = fmaxf(m2, rm * cexp);
            float al = exp2g(m2 - m2n);
            float rs = 0.f;
            #pragma unroll
            for (int r = 0; r < 16; ++r) {
                s0[r] = exp2g(__builtin_fmaf(s0[r], cexp, -m2n));
                s1[r] = exp2g(__builtin_fmaf(s1[r], cexp, -m2n));
                rs += s0[r] + s1[r];
            }
            rs += __shfl_xor(rs, 32);
            l_ = l_ * al + rs;
            m2 = m2n;
            #pragma unroll
            for (int n = 0; n < 4; ++n)
                #pragma unroll
                for (int r = 0; r < 16; ++r) o[n][r] *= al;

            // pack P (f32 -> bf16 u32 pairs), group g holds keys 8g+4hi+{0..3}
            unsigned pk0[4][2], pk1[4][2];
            #pragma unroll
            for (int g = 0; g < 4; ++g) {
                pk0[g][0] = pack2bf(s0[4*g],   s0[4*g+1]);
                pk0[g][1] = pack2bf(s0[4*g+2], s0[4*g+3]);
                pk1[g][0] = pack2bf(s1[4*g],   s1[4*g+1]);
                pk1[g][1] = pack2bf(s1[4*g+2], s1[4*g+3]);
            }
            const bool hb = (hi != 0);
            // PV (swapped): per 16-key block kb, B-frag = P[q=l31][kb*16+hi*8+j].
            #pragma unroll
            for (int kb = 0; kb < 4; ++kb) {
                const int g0 = (kb & 1) * 2;
                unsigned la, lb, oa, ob;
                if (kb < 2) { la = pk0[g0][0]; lb = pk0[g0][1]; oa = pk0[g0+1][0]; ob = pk0[g0+1][1]; }
                else        { la = pk1[g0][0]; lb = pk1[g0][1]; oa = pk1[g0+1][0]; ob = pk1[g0+1][1]; }
                unsigned sa0 = hb ? la : oa, sa1 = hb ? lb : ob;       // send grp g0+(1-hi)
                unsigned ra0 = (unsigned)__shfl_xor((int)sa0, 32);     // recv partner grp g0+hi
                unsigned ra1 = (unsigned)__shfl_xor((int)sa1, 32);
                unsigned ma0 = hb ? oa : la, ma1 = hb ? ob : lb;       // my grp g0+hi
                union { unsigned u[4]; v8bf v; } pf;
                pf.u[0] = hb ? ra0 : ma0; pf.u[1] = hb ? ra1 : ma1;    // j=0..3 (half 0)
                pf.u[2] = hb ? ma0 : ra0; pf.u[3] = hb ? ma1 : ra1;    // j=4..7 (half 1)
                #pragma unroll
                for (int n = 0; n < 4; ++n) {
                    v8bf av = *(const v8bf*)&Vt[(size_t)(n * 32 + l31) * 64 + ((kb * 16 + hi * 8) ^ vsw)];
                    o[n] = __builtin_amdgcn_mfma_f32_32x32x16_bf16(av, pf.v, o[n], 0, 0, 0);
                }
            }
        }

        // epilogue: lane owns q = qbase+l31, d = n*32+(r&3)+8*(r>>2)+4*hi
        float inv = 1.0f / l_;
        int q = qbase + l31;
        size_t obase = ((size_t)(b * S_ + q)) * HID_ + h * D_;
        #pragma unroll
        for (int n = 0; n < 4; ++n)
            #pragma unroll
            for (int rg = 0; rg < 4; ++rg) {
                ushort4 st;
                st.x = f2bf(o[n][4*rg+0] * inv);
                st.y = f2bf(o[n][4*rg+1] * inv);
                st.z = f2bf(o[n][4*rg+2] * inv);
                st.w = f2bf(o[n][4*rg+3] * inv);
                *(ushort4*)&O[obase + n * 32 + 8 * rg + 4 * hi] = st;
            }
    }
}

// ---------------- launcher ------------------------------------------------
extern "C" void kernel_launch(void* const* d_in, const int* in_sizes, int n_in,
                              void* d_out, int out_size, void* d_ws, size_t ws_size,
                              hipStream_t stream) {
    const float* hid  = (const float*)d_in[0];
    const float* Wq   = (const float*)d_in[1];
    const float* Wk   = (const float*)d_in[2];
    const float* Wv   = (const float*)d_in[3];
    const float* Wo   = (const float*)d_in[4];
    const float* cosc = (const float*)d_in[5];
    const float* sinc = (const float*)d_in[6];

    unsigned short* ws    = (unsigned short*)d_ws;
    unsigned short* wqkvT = ws;                                    // [6144][4096]
    unsigned short* qbuf  = ws + (size_t)NQKV_ * HID_;
    unsigned short* kbuf  = qbuf + (size_t)B_ * NH_ * S_ * D_;
    unsigned short* vbuf  = kbuf + (size_t)B_ * NKV_ * S_ * D_;
    unsigned short* hidB  = vbuf + (size_t)B_ * NKV_ * S_ * D_;
    unsigned short* attn  = ws;                                    // alias wqkvT
    unsigned short* woT   = ws + (size_t)M_ * HID_;                // alias tail
    unsigned short* vTbuf = hidB;                                  // alias hidB

    // 1. hidden fp32 -> bf16
    cvt_f32_bf16<<<(M_ * HID_ / 4 + 255) / 256, 256, 0, stream>>>(hid, hidB, M_ * HID_ / 4);
    // 2. W^T staging
    transpose_f32_bf16<<<dim3(64, 64), 256, 0, stream>>>(Wq, wqkvT, HID_, HID_);
    transpose_f32_bf16<<<dim3(16, 64), 256, 0, stream>>>(Wk, wqkvT + (size_t)HID_ * HID_, HID_, NKV_ * D_);
    transpose_f32_bf16<<<dim3(16, 64), 256, 0, stream>>>(Wv, wqkvT + (size_t)(HID_ + NKV_ * D_) * HID_, HID_, NKV_ * D_);
    // 3. fused QKV projection, scatter to per-head layouts
    gemm_bt<0><<<dim3(NQKV_ / 128, M_ / 128), 256, 0, stream>>>(
        hidB, wqkvT, HID_, HID_, HID_, qbuf, kbuf, vbuf, nullptr);
    // 4. RoPE (in-place) + V transpose
    rope_kernel<<<(B_ * NH_ * S_ * 64) / 256, 256, 0, stream>>>(qbuf, cosc, sinc, B_ * NH_ * S_ * 64);
    rope_kernel<<<(B_ * NKV_ * S_ * 64) / 256, 256, 0, stream>>>(kbuf, cosc, sinc, B_ * NKV_ * S_ * 64);
    transpose_v<<<dim3(S_ / 64, D_ / 64, B_ * NKV_), 256, 0, stream>>>(vbuf, vTbuf);
    // 5. causal flash attention v4 (paired q-tiles) -> attn [b,s,h*d] bf16
    flash_attn<<<dim3(8, NH_, B_), 256, 0, stream>>>(qbuf, kbuf, vTbuf, attn);
    // 6. O projection
    transpose_f32_bf16<<<dim3(64, 64), 256, 0, stream>>>(Wo, woT, HID_, HID_);
    gemm_bt<1><<<dim3(HID_ / 128, M_ / 128), 256, 0, stream>>>(
        attn, woT, HID_, HID_, HID_, nullptr, nullptr, nullptr, (float*)d_out);
}

// Round 7
// 1064.756 us; speedup vs baseline: 1.2833x; 1.0053x over previous
//
#include <hip/hip_runtime.h>

#define B_ 2
#define S_ 2048
#define HID_ 4096
#define NH_ 32
#define NKV_ 8
#define D_ 128
#define M_ (B_*S_)                  // 4096 rows of hidden
#define NQKV_ (HID_ + 2*NKV_*D_)    // 6144

typedef __bf16 v8bf __attribute__((ext_vector_type(8)));
typedef float  v4f  __attribute__((ext_vector_type(4)));
typedef float  v16f __attribute__((ext_vector_type(16)));

__device__ __forceinline__ unsigned short f2bf(float x) {
    unsigned u = __float_as_uint(x);
    u += 0x7FFFu + ((u >> 16) & 1u);   // RNE
    return (unsigned short)(u >> 16);
}
__device__ __forceinline__ float bf2f(unsigned short h) {
    return __uint_as_float(((unsigned)h) << 16);
}
// HW convert path: compiler emits v_cvt_pk_bf16_f32 for (__bf16) casts (m240)
__device__ __forceinline__ unsigned short bfbits(float x) {
    __bf16 b = (__bf16)x;
    return __builtin_bit_cast(unsigned short, b);
}
__device__ __forceinline__ unsigned pack2bf(float a, float b) {
    return (unsigned)bfbits(a) | ((unsigned)bfbits(b) << 16);
}
__device__ __forceinline__ float exp2g(float x) {
    return __builtin_amdgcn_exp2f(x);  // v_exp_f32: 2^x (avoids libm macro clash)
}

// async global->LDS, 16B per lane. LDS dest must be WAVE-UNIFORM base;
// HW writes base + lane*16. Global address is per-lane.
__device__ __forceinline__ void gl_lds16(const unsigned short* g, unsigned short* l) {
    __builtin_amdgcn_global_load_lds(
        (const __attribute__((address_space(1))) void*)g,
        (__attribute__((address_space(3))) void*)l, 16, 0, 0);
}

// ---------------- fp32 -> bf16 elementwise convert (x4 vectorized) ---------
__global__ __launch_bounds__(256)
void cvt_f32_bf16(const float* __restrict__ src, unsigned short* __restrict__ dst, int n4) {
    int i = blockIdx.x * 256 + threadIdx.x;
    if (i >= n4) return;
    float4 v = ((const float4*)src)[i];
    ushort4 o;
    o.x = f2bf(v.x); o.y = f2bf(v.y); o.z = f2bf(v.z); o.w = f2bf(v.w);
    ((ushort4*)dst)[i] = o;
}

// ------------- transpose+convert: dst[n][k] = bf16(src[k][n]), fp32 src ----
__global__ __launch_bounds__(256)
void transpose_f32_bf16(const float* __restrict__ src,
                        unsigned short* __restrict__ dst, int K, int N) {
    __shared__ unsigned short tile[64][65];
    int n0 = blockIdx.x * 64, k0 = blockIdx.y * 64;
    int tid = threadIdx.x;
    for (int i = 0; i < 16; ++i) {
        int fi = tid + i * 256;
        int r = fi >> 6, c = fi & 63;
        tile[r][c] = f2bf(src[(size_t)(k0 + r) * N + n0 + c]);
    }
    __syncthreads();
    for (int i = 0; i < 16; ++i) {
        int fi = tid + i * 256;
        int r = fi >> 6, c = fi & 63;
        dst[(size_t)(n0 + r) * K + k0 + c] = tile[c][r];
    }
}

// ------------- per-head V transpose: [BHkv][S][D] -> [BHkv][D][S] bf16 -----
__global__ __launch_bounds__(256)
void transpose_v(const unsigned short* __restrict__ src,
                 unsigned short* __restrict__ dst) {
    __shared__ unsigned short tile[64][65];
    int s0 = blockIdx.x * 64, d0 = blockIdx.y * 64;
    size_t base = (size_t)blockIdx.z * S_ * D_;
    int tid = threadIdx.x;
    for (int i = 0; i < 16; ++i) {
        int fi = tid + i * 256;
        int r = fi >> 6, c = fi & 63;            // r: s-offset, c: d-offset
        tile[r][c] = src[base + (size_t)(s0 + r) * D_ + d0 + c];
    }
    __syncthreads();
    for (int i = 0; i < 16; ++i) {
        int fi = tid + i * 256;
        int r = fi >> 6, c = fi & 63;            // r: d-offset, c: s-offset
        dst[base + (size_t)(d0 + r) * S_ + s0 + c] = tile[c][r];
    }
}

// ---------------- GEMM: C[M][N] = A[M][K] * BT[N][K]^T  (bf16 in, fp32 acc) -
// m97 structure: global_load_lds width-16 staging into LINEAR (unpadded) LDS.
template <int MODE>
__global__ __launch_bounds__(256)
void gemm_bt(const unsigned short* __restrict__ A,
             const unsigned short* __restrict__ BT,
             int K, int lda, int ldb,
             unsigned short* __restrict__ outQ,
             unsigned short* __restrict__ outK,
             unsigned short* __restrict__ outV,
             float* __restrict__ outF) {
    __shared__ unsigned short As[128][32];   // linear: gl_lds dest is base+lane*16
    __shared__ unsigned short Bs[128][32];
    int tid = threadIdx.x;
    int lane = tid & 63, wid = tid >> 6;
    int quad = lane >> 4, l16 = lane & 15;
    int wr = wid >> 1, wc = wid & 1;
    int r0 = blockIdx.y * 128, n0 = blockIdx.x * 128;

    v4f zero = {0.f, 0.f, 0.f, 0.f};
    v4f acc[4][4];
    for (int i = 0; i < 4; ++i) for (int j = 0; j < 4; ++j) acc[i][j] = zero;

    const int srow = wid * 32 + (lane >> 2);      // per-lane source row within tile
    const int sch  = (lane & 3) * 8;              // 16B chunk (8 shorts)
    const unsigned short* gA = &A [(size_t)(r0 + srow) * lda + sch];
    const unsigned short* gB = &BT[(size_t)(n0 + srow) * ldb + sch];
    unsigned short* lA0 = &As[wid * 32][0];
    unsigned short* lA1 = &As[wid * 32 + 16][0];
    unsigned short* lB0 = &Bs[wid * 32][0];
    unsigned short* lB1 = &Bs[wid * 32 + 16][0];

    for (int kt = 0; kt < K / 32; ++kt) {
        int kk = kt * 32;
        gl_lds16(gA + kk, lA0);
        gl_lds16(gA + (size_t)16 * lda + kk, lA1);
        gl_lds16(gB + kk, lB0);
        gl_lds16(gB + (size_t)16 * ldb + kk, lB1);
        __syncthreads();
        v8bf av[4], bv[4];
        for (int ms = 0; ms < 4; ++ms) av[ms] = *(const v8bf*)&As[wr * 64 + ms * 16 + l16][quad * 8];
        for (int ns = 0; ns < 4; ++ns) bv[ns] = *(const v8bf*)&Bs[wc * 64 + ns * 16 + l16][quad * 8];
        for (int ms = 0; ms < 4; ++ms)
            for (int ns = 0; ns < 4; ++ns)
                acc[ms][ns] = __builtin_amdgcn_mfma_f32_16x16x32_bf16(av[ms], bv[ns], acc[ms][ns], 0, 0, 0);
        __syncthreads();
    }

    for (int ms = 0; ms < 4; ++ms)
        for (int ns = 0; ns < 4; ++ns)
            for (int r = 0; r < 4; ++r) {
                int row = r0 + wr * 64 + ms * 16 + quad * 4 + r;   // C row = quad*4+reg (m89)
                int col = n0 + wc * 64 + ns * 16 + l16;            // C col = lane&15
                if (MODE == 1) {
                    outF[(size_t)row * HID_ + col] = acc[ms][ns][r];
                } else {
                    unsigned short hv = f2bf(acc[ms][ns][r]);
                    int b = row >> 11, s = row & (S_ - 1);
                    if (col < HID_) {
                        int h = col >> 7, d = col & 127;
                        outQ[((size_t)((b * NH_ + h) * S_ + s)) * D_ + d] = hv;
                    } else if (col < HID_ + NKV_ * D_) {
                        int j = col - HID_; int h = j >> 7, d = j & 127;
                        outK[((size_t)((b * NKV_ + h) * S_ + s)) * D_ + d] = hv;
                    } else {
                        int j = col - HID_ - NKV_ * D_; int h = j >> 7, d = j & 127;
                        outV[((size_t)((b * NKV_ + h) * S_ + s)) * D_ + d] = hv;
                    }
                }
            }
}

// ---------------- RoPE in-place on [BH][S][D] bf16, fp32 cos/sin ----------
__global__ __launch_bounds__(256)
void rope_kernel(unsigned short* __restrict__ buf,
                 const float* __restrict__ cosc,
                 const float* __restrict__ sinc, int total) {
    int idx = blockIdx.x * 256 + threadIdx.x;
    if (idx >= total) return;
    int d2 = idx & 63;
    int s  = (idx >> 6) & (S_ - 1);
    int bh = idx >> 17;                       // /(64*2048)
    size_t base = ((size_t)bh * S_ + s) * D_;
    float c  = cosc[s * D_ + d2];             // cos[s][d2] == cos[s][d2+64]
    float sn = sinc[s * D_ + d2];
    float x1 = bf2f(buf[base + d2]);
    float x2 = bf2f(buf[base + d2 + 64]);
    buf[base + d2]      = f2bf(x1 * c - x2 * sn);
    buf[base + d2 + 64] = f2bf(x2 * c + x1 * sn);
}

// ---------------- causal flash attention v5 --------------------------------
// v4 (paired q-tiles, swapped QK^T/PV, in-register P) + VALU diet:
//  - P pack & epilogue via (__bf16) casts -> compiler emits v_cvt_pk_bf16_f32
//  - s_setprio(1) around MFMA clusters (T5)
//  - defer-max (T13, THR=8 nats): skip O/l rescale when max didn't grow
__global__ __launch_bounds__(256)
void flash_attn(const unsigned short* __restrict__ Q,
                const unsigned short* __restrict__ Kb,
                const unsigned short* __restrict__ VT,
                unsigned short* __restrict__ O) {
    __shared__ unsigned short Ks[64 * 128];   // [key][d], swizzled
    __shared__ unsigned short Vt[128 * 64];   // [d][key], swizzled
    int tid = threadIdx.x;
    int lane = tid & 63, w = tid >> 6;
    int l31 = lane & 31, hi = lane >> 5;
    int p = blockIdx.x;                       // 0..7
    int h = blockIdx.y, b = blockIdx.z;

    const int hkv = h >> 2;                                  // GROUPS=4
    const size_t kvbase = (size_t)(b * NKV_ + hkv) * S_ * D_;
    const size_t vtbase = kvbase;                            // [D][S] extent

    // staging: K = 64 rows x 16 chunks, V = 128 rows x 8 chunks (16B chunks)
    int krow[4], kch[4], vrow[4], vch[4];
    #pragma unroll
    for (int i = 0; i < 4; ++i) {
        int idx = tid + i * 256;
        krow[i] = idx >> 4; kch[i] = idx & 15;
        vrow[i] = idx >> 3; vch[i] = idx & 7;
    }
    const int vsw = (l31 & 7) << 3;           // read-side swizzle

    for (int ph = 0; ph < 2; ++ph) {
        const int qt = ph == 0 ? 15 - p : p;  // long tile first
        const int qbase = qt * 128 + w * 32;

        // Q B-fragments: n = q = qbase+l31, k = kt*16 + hi*8 + j
        const size_t qoff = ((size_t)(b * NH_ + h) * S_ + qbase + l31) * D_ + hi * 8;
        v8bf aq[8];
        #pragma unroll
        for (int kt = 0; kt < 8; ++kt) aq[kt] = *(const v8bf*)&Q[qoff + kt * 16];

        v16f o[4];
        #pragma unroll
        for (int n = 0; n < 4; ++n)
            #pragma unroll
            for (int r = 0; r < 16; ++r) o[n][r] = 0.f;
        float m2 = -1e30f, l_ = 0.f;          // running max/denom, exp2 domain

        const int ntB = 2 * qt + 2;           // block-level KV tiles
        const int twmax = (qbase + 31) >> 6;  // last tile this wave computes

        uint4 kpre[4], vpre[4];
        #pragma unroll
        for (int i = 0; i < 4; ++i) {
            kpre[i] = *(const uint4*)&Kb[kvbase + (size_t)krow[i] * D_ + kch[i] * 8];
            vpre[i] = *(const uint4*)&VT[vtbase + (size_t)vrow[i] * S_ + vch[i] * 8];
        }

        for (int t = 0; t < ntB; ++t) {
            int kv0 = t * 64;
            __syncthreads();                  // previous tile's readers done
            #pragma unroll
            for (int i = 0; i < 4; ++i) {
                *(uint4*)&Ks[(size_t)krow[i] * 128 + ((kch[i] * 8) ^ ((krow[i] & 7) << 3))] = kpre[i];
                *(uint4*)&Vt[(size_t)vrow[i] * 64 + ((vch[i] * 8) ^ ((vrow[i] & 7) << 3))] = vpre[i];
            }
            __syncthreads();
            if (t + 1 < ntB) {                // prefetch next tile
                int nkv0 = kv0 + 64;
                #pragma unroll
                for (int i = 0; i < 4; ++i) {
                    kpre[i] = *(const uint4*)&Kb[kvbase + (size_t)(nkv0 + krow[i]) * D_ + kch[i] * 8];
                    vpre[i] = *(const uint4*)&VT[vtbase + (size_t)vrow[i] * S_ + nkv0 + vch[i] * 8];
                }
            }
            if (t > twmax) continue;          // fully-masked tile: barriers done

            // QK^T (swapped): S^T[key][q], key = kv0 + kb32*32 + (r&3)+8*(r>>2)+4*hi
            v16f s0, s1;
            #pragma unroll
            for (int r = 0; r < 16; ++r) { s0[r] = 0.f; s1[r] = 0.f; }
            __builtin_amdgcn_s_setprio(1);
            #pragma unroll
            for (int kt = 0; kt < 8; ++kt) {
                int cw = (kt * 16 + hi * 8) ^ ((l31 & 7) << 3);   // read-side swizzle
                v8bf k0 = *(const v8bf*)&Ks[(size_t)l31 * 128 + cw];
                v8bf k1 = *(const v8bf*)&Ks[(size_t)(32 + l31) * 128 + cw];
                s0 = __builtin_amdgcn_mfma_f32_32x32x16_bf16(k0, aq[kt], s0, 0, 0, 0);
                s1 = __builtin_amdgcn_mfma_f32_32x32x16_bf16(k1, aq[kt], s1, 0, 0, 0);
            }
            __builtin_amdgcn_s_setprio(0);

            if (kv0 + 63 > qbase) {           // diagonal tile: causal mask
                int vq = qbase + l31 - kv0 - 4 * hi;
                #pragma unroll
                for (int r = 0; r < 16; ++r) {
                    int c0 = (r & 3) + 8 * (r >> 2);
                    if (c0 > vq)      s0[r] = -1e30f;
                    if (c0 + 32 > vq) s1[r] = -1e30f;
                }
            }
            // row max: 32 in-reg values + cross-half exchange (q is lane-local)
            float rm = fmaxf(s0[0], s1[0]);
            #pragma unroll
            for (int r = 1; r < 16; ++r) rm = fmaxf(fmaxf(rm, s0[r]), s1[r]);  // v_max3
            rm = fmaxf(rm, __shfl_xor(rm, 32));
            const float cexp = 0.1275279431f; // log2(e)/sqrt(128)
            // defer-max: only rescale when the max grew by > 8 nats (11.54 in 2^)
            float d = rm * cexp - m2;
            if (__any(d > 11.5416f)) {
                float m2n = fmaxf(m2, rm * cexp);
                float al = exp2g(m2 - m2n);
                l_ *= al;
                #pragma unroll
                for (int n = 0; n < 4; ++n)
                    #pragma unroll
                    for (int r = 0; r < 16; ++r) o[n][r] *= al;
                m2 = m2n;
            }
            float rs = 0.f;
            #pragma unroll
            for (int r = 0; r < 16; ++r) {
                s0[r] = exp2g(__builtin_fmaf(s0[r], cexp, -m2));
                s1[r] = exp2g(__builtin_fmaf(s1[r], cexp, -m2));
                rs += s0[r] + s1[r];
            }
            rs += __shfl_xor(rs, 32);
            l_ += rs;

            // pack P (f32 -> bf16 u32 pairs via v_cvt_pk), grp g = keys 8g+4hi+{0..3}
            unsigned pk0[4][2], pk1[4][2];
            #pragma unroll
            for (int g = 0; g < 4; ++g) {
                pk0[g][0] = pack2bf(s0[4*g],   s0[4*g+1]);
                pk0[g][1] = pack2bf(s0[4*g+2], s0[4*g+3]);
                pk1[g][0] = pack2bf(s1[4*g],   s1[4*g+1]);
                pk1[g][1] = pack2bf(s1[4*g+2], s1[4*g+3]);
            }
            const bool hb = (hi != 0);
            // PV (swapped): per 16-key block kb, B-frag = P[q=l31][kb*16+hi*8+j].
            #pragma unroll
            for (int kb = 0; kb < 4; ++kb) {
                const int g0 = (kb & 1) * 2;
                unsigned la, lb, oa, ob;
                if (kb < 2) { la = pk0[g0][0]; lb = pk0[g0][1]; oa = pk0[g0+1][0]; ob = pk0[g0+1][1]; }
                else        { la = pk1[g0][0]; lb = pk1[g0][1]; oa = pk1[g0+1][0]; ob = pk1[g0+1][1]; }
                unsigned sa0 = hb ? la : oa, sa1 = hb ? lb : ob;       // send grp g0+(1-hi)
                unsigned ra0 = (unsigned)__shfl_xor((int)sa0, 32);     // recv partner grp g0+hi
                unsigned ra1 = (unsigned)__shfl_xor((int)sa1, 32);
                unsigned ma0 = hb ? oa : la, ma1 = hb ? ob : lb;       // my grp g0+hi
                union { unsigned u[4]; v8bf v; } pf;
                pf.u[0] = hb ? ra0 : ma0; pf.u[1] = hb ? ra1 : ma1;    // j=0..3 (half 0)
                pf.u[2] = hb ? ma0 : ra0; pf.u[3] = hb ? ma1 : ra1;    // j=4..7 (half 1)
                __builtin_amdgcn_s_setprio(1);
                #pragma unroll
                for (int n = 0; n < 4; ++n) {
                    v8bf av = *(const v8bf*)&Vt[(size_t)(n * 32 + l31) * 64 + ((kb * 16 + hi * 8) ^ vsw)];
                    o[n] = __builtin_amdgcn_mfma_f32_32x32x16_bf16(av, pf.v, o[n], 0, 0, 0);
                }
                __builtin_amdgcn_s_setprio(0);
            }
        }

        // epilogue: lane owns q = qbase+l31, d = n*32+(r&3)+8*(r>>2)+4*hi
        float inv = 1.0f / l_;
        int q = qbase + l31;
        size_t obase = ((size_t)(b * S_ + q)) * HID_ + h * D_;
        #pragma unroll
        for (int n = 0; n < 4; ++n)
            #pragma unroll
            for (int rg = 0; rg < 4; ++rg) {
                ushort4 st;
                st.x = bfbits(o[n][4*rg+0] * inv);
                st.y = bfbits(o[n][4*rg+1] * inv);
                st.z = bfbits(o[n][4*rg+2] * inv);
                st.w = bfbits(o[n][4*rg+3] * inv);
                *(ushort4*)&O[obase + n * 32 + 8 * rg + 4 * hi] = st;
            }
    }
}

// ---------------- launcher ------------------------------------------------
extern "C" void kernel_launch(void* const* d_in, const int* in_sizes, int n_in,
                              void* d_out, int out_size, void* d_ws, size_t ws_size,
                              hipStream_t stream) {
    const float* hid  = (const float*)d_in[0];
    const float* Wq   = (const float*)d_in[1];
    const float* Wk   = (const float*)d_in[2];
    const float* Wv   = (const float*)d_in[3];
    const float* Wo   = (const float*)d_in[4];
    const float* cosc = (const float*)d_in[5];
    const float* sinc = (const float*)d_in[6];

    unsigned short* ws    = (unsigned short*)d_ws;
    unsigned short* wqkvT = ws;                                    // [6144][4096]
    unsigned short* qbuf  = ws + (size_t)NQKV_ * HID_;
    unsigned short* kbuf  = qbuf + (size_t)B_ * NH_ * S_ * D_;
    unsigned short* vbuf  = kbuf + (size_t)B_ * NKV_ * S_ * D_;
    unsigned short* hidB  = vbuf + (size_t)B_ * NKV_ * S_ * D_;
    unsigned short* attn  = ws;                                    // alias wqkvT
    unsigned short* woT   = ws + (size_t)M_ * HID_;                // alias tail
    unsigned short* vTbuf = hidB;                                  // alias hidB

    // 1. hidden fp32 -> bf16
    cvt_f32_bf16<<<(M_ * HID_ / 4 + 255) / 256, 256, 0, stream>>>(hid, hidB, M_ * HID_ / 4);
    // 2. W^T staging
    transpose_f32_bf16<<<dim3(64, 64), 256, 0, stream>>>(Wq, wqkvT, HID_, HID_);
    transpose_f32_bf16<<<dim3(16, 64), 256, 0, stream>>>(Wk, wqkvT + (size_t)HID_ * HID_, HID_, NKV_ * D_);
    transpose_f32_bf16<<<dim3(16, 64), 256, 0, stream>>>(Wv, wqkvT + (size_t)(HID_ + NKV_ * D_) * HID_, HID_, NKV_ * D_);
    // 3. fused QKV projection, scatter to per-head layouts
    gemm_bt<0><<<dim3(NQKV_ / 128, M_ / 128), 256, 0, stream>>>(
        hidB, wqkvT, HID_, HID_, HID_, qbuf, kbuf, vbuf, nullptr);
    // 4. RoPE (in-place) + V transpose
    rope_kernel<<<(B_ * NH_ * S_ * 64) / 256, 256, 0, stream>>>(qbuf, cosc, sinc, B_ * NH_ * S_ * 64);
    rope_kernel<<<(B_ * NKV_ * S_ * 64) / 256, 256, 0, stream>>>(kbuf, cosc, sinc, B_ * NKV_ * S_ * 64);
    transpose_v<<<dim3(S_ / 64, D_ / 64, B_ * NKV_), 256, 0, stream>>>(vbuf, vTbuf);
    // 5. causal flash attention v5 -> attn [b,s,h*d] bf16
    flash_attn<<<dim3(8, NH_, B_), 256, 0, stream>>>(qbuf, kbuf, vTbuf, attn);
    // 6. O projection
    transpose_f32_bf16<<<dim3(64, 64), 256, 0, stream>>>(Wo, woT, HID_, HID_);
    gemm_bt<1><<<dim3(HID_ / 128, M_ / 128), 256, 0, stream>>>(
        attn, woT, HID_, HID_, HID_, nullptr, nullptr, nullptr, (float*)d_out);
}